// Round 34
// baseline (137.465 us; speedup 1.0000x reference)
//
#include <hip/hip_runtime.h>
#include <hip/hip_bf16.h>

#define BB 2
#define SS 2048
#define NH 32
#define NKV 8
#define GQ (NH / NKV)
#define DD 128
#define QBLK 256
#define KVBLK 64
#define NQT (SS / QBLK)
#define NTHREADS 512
#define NWAVES 8

// +8 shorts (16B) padding on LDS leading dims.
#define KPAD (DD + 8)
#define VPAD (KVBLK + 8)

typedef __bf16 bf16x8 __attribute__((ext_vector_type(8)));
typedef short short8 __attribute__((ext_vector_type(8)));
typedef float f32x4 __attribute__((ext_vector_type(4)));
typedef unsigned int u32x4 __attribute__((ext_vector_type(4)));

__device__ inline bf16x8 cvt_bf16x8(float4 a, float4 b) {
  bf16x8 r;
  r[0] = (__bf16)a.x; r[1] = (__bf16)a.y; r[2] = (__bf16)a.z; r[3] = (__bf16)a.w;
  r[4] = (__bf16)b.x; r[5] = (__bf16)b.y; r[6] = (__bf16)b.z; r[7] = (__bf16)b.w;
  return r;
}

// R30/R33 (124.4us anchor) + l-VIA-MFMA: the softmax row-sum l is computed
// by one extra MFMA per kc2 with an ALL-ONES B-operand — C[q][*]=sum_t P.
// Deletes per subtile per tile: the 16-add ss chain + 2 shfl_xor LDS hops,
// AND the epilogue's cross-lane l reduce (lacc[u][jj] already sits at the
// epilogue's (lhi,jj) indexing). +4 MFMAs/tile on the 18%-busy matrix pipe.
// Rescale path scales lacc alongside oacc with the same row-uniform corr.
__global__ __launch_bounds__(NTHREADS, 2)
void attn_mfma_lmm(const float* __restrict__ qp, const float* __restrict__ kp,
                   const float* __restrict__ vp, float* __restrict__ op)
{
  __shared__ __align__(16) short kpl[2][KVBLK][KPAD];    // 34.8KB
  __shared__ __align__(16) short vtp[2][DD][VPAD];       // 36.9KB

  const int tid  = threadIdx.x;
  const int wave = tid >> 6;
  const int lane = tid & 63;
  const int lhi  = lane >> 4;
  const int llo  = lane & 15;

  const int bid = blockIdx.x;
  const int bh  = bid % (BB * NH);
  const int qt  = NQT - 1 - bid / (BB * NH);   // heavy q-tiles first
  const int b   = bh / NH;
  const int h   = bh % NH;
  const int kh  = h / GQ;

  const int q0 = qt * QBLK;
  const int qw = q0 + wave * 32;               // this wave's 32 rows

  const float scale = 0.08838834764831845f;    // 1/sqrt(128), natural domain

  // all-ones bf16 B-operand for the l-row-sum MFMA
  bf16x8 ones;
  #pragma unroll
  for (int i = 0; i < 8; ++i) ones[i] = (__bf16)1.0f;

  // ---- Q fragments for both subtiles ----
  bf16x8 qf[2][4];
  #pragma unroll
  for (int u = 0; u < 2; ++u) {
    const float* qrow = qp + (((size_t)b * SS + (qw + u * 16 + llo)) * NH + h) * DD;
    #pragma unroll
    for (int kc = 0; kc < 4; ++kc) {
      const int d0 = kc * 32 + lhi * 8;
      float4 a = *(const float4*)(qrow + d0);
      float4 c = *(const float4*)(qrow + d0 + 4);
      a.x *= scale; a.y *= scale; a.z *= scale; a.w *= scale;
      c.x *= scale; c.y *= scale; c.z *= scale; c.w *= scale;
      qf[u][kc] = cvt_bf16x8(a, c);
    }
  }

  f32x4 oacc[2][8];
  f32x4 lacc[2];
  #pragma unroll
  for (int u = 0; u < 2; ++u) {
    #pragma unroll
    for (int f = 0; f < 8; ++f) oacc[u][f] = (f32x4){0.f, 0.f, 0.f, 0.f};
    lacc[u] = (f32x4){0.f, 0.f, 0.f, 0.f};
  }
  float m_i[2] = {-1e30f, -1e30f};

  const int ntiles = q0 / KVBLK + QBLK / KVBLK;

  for (int tt = 0; tt <= ntiles; ++tt) {
    // ---- stage tile tt into buf[tt&1] ----
    if (tt < ntiles) {
      const int t0 = tt * KVBLK;
      const int sb = tt & 1;
      // K (bf16, permuted row placement): 2 x 16B store per thread
      #pragma unroll
      for (int it = 0; it < 2; ++it) {
        const int c   = tid + it * NTHREADS;   // 0..1023
        const int row = c >> 4, c16 = c & 15;
        // r(t): bits {t5, t2, t4, t3, t1, t0}
        const int prow = (row & 32) | ((row & 4) << 2) | ((row & 24) >> 1) | (row & 3);
        const float* src = kp + (((size_t)b * SS + (t0 + row)) * NKV + kh) * DD + c16 * 8;
        float4 a = *(const float4*)src;
        float4 d = *(const float4*)(src + 4);
        *(u32x4*)&kpl[sb][prow][c16 * 8] = __builtin_bit_cast(u32x4, cvt_bf16x8(a, d));
      }
      // V^T: coalesced per-t dword loads -> b128 row-seg writes
      #pragma unroll
      for (int it = 0; it < 2; ++it) {
        const int c  = tid + it * NTHREADS;    // 0..1023
        const int dv = c & 127, t8 = c >> 7;   // d, t-octet
        const float* src = vp + (((size_t)b * SS + (t0 + t8 * 8)) * NKV + kh) * DD + dv;
        bf16x8 e;
        #pragma unroll
        for (int i2 = 0; i2 < 8; ++i2)
          e[i2] = (__bf16)src[(size_t)i2 * (NKV * DD)];
        *(u32x4*)&vtp[sb][dv][t8 * 8] = __builtin_bit_cast(u32x4, e);
      }
    }

    // ---- compute tile ct = tt-1 from buf[ct&1] ----
    if (tt >= 1) {
      const int ct  = tt - 1;
      const int t0c = ct * KVBLK;
      const int cb  = ct & 1;
      if (t0c <= qw + 31) {
        // QK^T swapped, both subtiles share each K read.
        f32x4 sf[2][4];
        #pragma unroll
        for (int cc = 0; cc < 4; ++cc) {
          f32x4 a0 = (f32x4){0.f, 0.f, 0.f, 0.f};
          f32x4 a1 = (f32x4){0.f, 0.f, 0.f, 0.f};
          const int r = cc * 16 + llo;         // permuted K row for A-fragment
          #pragma unroll
          for (int kc = 0; kc < 4; ++kc) {
            u32x4 kb = *(const u32x4*)&kpl[cb][r][(kc * 4 + lhi) * 8];
            const bf16x8 kf = __builtin_bit_cast(bf16x8, kb);
            a0 = __builtin_amdgcn_mfma_f32_16x16x32_bf16(kf, qf[0][kc], a0, 0, 0, 0);
            a1 = __builtin_amdgcn_mfma_f32_16x16x32_bf16(kf, qf[1][kc], a1, 0, 0, 0);
          }
          sf[0][cc] = a0; sf[1][cc] = a1;
        }

        // causal mask (permuted t mapping)
        if (t0c + KVBLK - 1 > qw) {
          #pragma unroll
          for (int u = 0; u < 2; ++u) {
            const int qg = qw + u * 16 + llo;
            #pragma unroll
            for (int cc = 0; cc < 4; ++cc)
              #pragma unroll
              for (int jj = 0; jj < 4; ++jj) {
                const int tg = t0c + (cc >> 1) * 32 + lhi * 8 + (cc & 1) * 4 + jj;
                if (tg > qg) sf[u][cc][jj] = -1e30f;
              }
          }
        }

        // online softmax with defer-max; NO sum chain (l comes from MFMA)
        #pragma unroll
        for (int u = 0; u < 2; ++u) {
          float tmx = sf[u][0][0];
          #pragma unroll
          for (int cc = 0; cc < 4; ++cc)
            #pragma unroll
            for (int jj = 0; jj < 4; ++jj)
              tmx = fmaxf(tmx, sf[u][cc][jj]);
          tmx = fmaxf(tmx, __shfl_xor(tmx, 16));
          tmx = fmaxf(tmx, __shfl_xor(tmx, 32));

          if (!__all(tmx - m_i[u] <= 5.5f)) {
            const float mnew = fmaxf(m_i[u], tmx);
            const float corr = __expf(m_i[u] - mnew);
            m_i[u] = mnew;
            #pragma unroll
            for (int jj = 0; jj < 4; ++jj) {
              const float cj = __shfl(corr, lhi * 4 + jj);
              lacc[u][jj] *= cj;
              #pragma unroll
              for (int f = 0; f < 8; ++f) oacc[u][f][jj] *= cj;
            }
          }
          const float base = m_i[u];
          #pragma unroll
          for (int cc = 0; cc < 4; ++cc)
            #pragma unroll
            for (int jj = 0; jj < 4; ++jj)
              sf[u][cc][jj] = __expf(sf[u][cc][jj] - base);  // <= e^5.5 ~ 244
        }

        // PV + l-row-sum: pa(kc2) lane-local; lacc += pa * ones
        #pragma unroll
        for (int kc2 = 0; kc2 < 2; ++kc2) {
          bf16x8 pa[2];
          #pragma unroll
          for (int u = 0; u < 2; ++u) {
            pa[u][0] = (__bf16)sf[u][2 * kc2][0];
            pa[u][1] = (__bf16)sf[u][2 * kc2][1];
            pa[u][2] = (__bf16)sf[u][2 * kc2][2];
            pa[u][3] = (__bf16)sf[u][2 * kc2][3];
            pa[u][4] = (__bf16)sf[u][2 * kc2 + 1][0];
            pa[u][5] = (__bf16)sf[u][2 * kc2 + 1][1];
            pa[u][6] = (__bf16)sf[u][2 * kc2 + 1][2];
            pa[u][7] = (__bf16)sf[u][2 * kc2 + 1][3];
          }
          lacc[0] = __builtin_amdgcn_mfma_f32_16x16x32_bf16(pa[0], ones, lacc[0], 0, 0, 0);
          lacc[1] = __builtin_amdgcn_mfma_f32_16x16x32_bf16(pa[1], ones, lacc[1], 0, 0, 0);
          #pragma unroll
          for (int f = 0; f < 8; ++f) {
            u32x4 vb = *(const u32x4*)&vtp[cb][f * 16 + llo][(kc2 * 4 + lhi) * 8];
            const bf16x8 vf = __builtin_bit_cast(bf16x8, vb);
            oacc[0][f] = __builtin_amdgcn_mfma_f32_16x16x32_bf16(pa[0], vf, oacc[0][f], 0, 0, 0);
            oacc[1][f] = __builtin_amdgcn_mfma_f32_16x16x32_bf16(pa[1], vf, oacc[1][f], 0, 0, 0);
          }
        }
      }
    }

    __syncthreads();   // buf[tt&1] staged for all; buf[(tt-1)&1] reusable
  }

  // ---- epilogue: O / l — l sits at (lhi,jj) already, NO cross-lane reduce ----
  #pragma unroll
  for (int u = 0; u < 2; ++u)
    #pragma unroll
    for (int jj = 0; jj < 4; ++jj) {
      const float inv = 1.f / lacc[u][jj];
      const int qg = qw + u * 16 + lhi * 4 + jj;
      float* orow = op + (((size_t)b * SS + qg) * NH + h) * DD;
      #pragma unroll
      for (int f = 0; f < 8; ++f)
        orow[f * 16 + llo] = oacc[u][f][jj] * inv;
    }
}

extern "C" void kernel_launch(void* const* d_in, const int* in_sizes, int n_in,
                              void* d_out, int out_size, void* d_ws, size_t ws_size,
                              hipStream_t stream) {
  const float* q = (const float*)d_in[0];
  const float* k = (const float*)d_in[1];
  const float* v = (const float*)d_in[2];
  float* out = (float*)d_out;
  dim3 grid(BB * NH * NQT);   // 512 blocks, heavy-first linear dispatch
  dim3 block(NTHREADS);
  attn_mfma_lmm<<<grid, block, 0, stream>>>(q, k, v, out);
}

// Round 35
// 123.877 us; speedup vs baseline: 1.1097x; 1.1097x over previous
//
#include <hip/hip_runtime.h>
#include <hip/hip_bf16.h>

#define BB 2
#define SS 2048
#define NH 32
#define NKV 8
#define GQ (NH / NKV)
#define DD 128
#define QBLK 256
#define KVBLK 64
#define NQT (SS / QBLK)
#define NTHREADS 512
#define NWAVES 8

// +8 shorts (16B) padding on LDS leading dims.
#define KPAD (DD + 8)
#define VPAD (KVBLK + 8)

typedef __bf16 bf16x8 __attribute__((ext_vector_type(8)));
typedef short short8 __attribute__((ext_vector_type(8)));
typedef float f32x4 __attribute__((ext_vector_type(4)));
typedef unsigned int u32x4 __attribute__((ext_vector_type(4)));

__device__ inline bf16x8 cvt_bf16x8(float4 a, float4 b) {
  bf16x8 r;
  r[0] = (__bf16)a.x; r[1] = (__bf16)a.y; r[2] = (__bf16)a.z; r[3] = (__bf16)a.w;
  r[4] = (__bf16)b.x; r[5] = (__bf16)b.y; r[6] = (__bf16)b.z; r[7] = (__bf16)b.w;
  return r;
}

// R30/R33 (124.4us anchor) + ONLY `#pragma unroll 2` on the tile loop:
// the tt&1 / ct&1 buffer selectors become compile-time constants in each
// unrolled copy -> LDS bases fold to immediates, and the scheduler gets a
// 2-tile window to interleave staging VMEM with the previous tile's
// compute. No semantic change. (R34's l-via-MFMA reverted: +4 serial
// MFMAs/tile cost more than the sum chain it replaced, 137us.)
__global__ __launch_bounds__(NTHREADS, 2)
void attn_mfma_u2(const float* __restrict__ qp, const float* __restrict__ kp,
                  const float* __restrict__ vp, float* __restrict__ op)
{
  __shared__ __align__(16) short kpl[2][KVBLK][KPAD];    // 34.8KB
  __shared__ __align__(16) short vtp[2][DD][VPAD];       // 36.9KB

  const int tid  = threadIdx.x;
  const int wave = tid >> 6;
  const int lane = tid & 63;
  const int lhi  = lane >> 4;
  const int llo  = lane & 15;

  const int bid = blockIdx.x;
  const int bh  = bid % (BB * NH);
  const int qt  = NQT - 1 - bid / (BB * NH);   // heavy q-tiles first
  const int b   = bh / NH;
  const int h   = bh % NH;
  const int kh  = h / GQ;

  const int q0 = qt * QBLK;
  const int qw = q0 + wave * 32;               // this wave's 32 rows

  const float scale = 0.08838834764831845f;    // 1/sqrt(128), natural domain

  // ---- Q fragments for both subtiles ----
  bf16x8 qf[2][4];
  #pragma unroll
  for (int u = 0; u < 2; ++u) {
    const float* qrow = qp + (((size_t)b * SS + (qw + u * 16 + llo)) * NH + h) * DD;
    #pragma unroll
    for (int kc = 0; kc < 4; ++kc) {
      const int d0 = kc * 32 + lhi * 8;
      float4 a = *(const float4*)(qrow + d0);
      float4 c = *(const float4*)(qrow + d0 + 4);
      a.x *= scale; a.y *= scale; a.z *= scale; a.w *= scale;
      c.x *= scale; c.y *= scale; c.z *= scale; c.w *= scale;
      qf[u][kc] = cvt_bf16x8(a, c);
    }
  }

  f32x4 oacc[2][8];
  #pragma unroll
  for (int u = 0; u < 2; ++u)
    #pragma unroll
    for (int f = 0; f < 8; ++f) oacc[u][f] = (f32x4){0.f, 0.f, 0.f, 0.f};
  float m_i[2] = {-1e30f, -1e30f}, l_i[2] = {0.f, 0.f};

  const int ntiles = q0 / KVBLK + QBLK / KVBLK;

  #pragma unroll 2
  for (int tt = 0; tt <= ntiles; ++tt) {
    // ---- stage tile tt into buf[tt&1] ----
    if (tt < ntiles) {
      const int t0 = tt * KVBLK;
      const int sb = tt & 1;
      // K (bf16, permuted row placement): 2 x 16B store per thread
      #pragma unroll
      for (int it = 0; it < 2; ++it) {
        const int c   = tid + it * NTHREADS;   // 0..1023
        const int row = c >> 4, c16 = c & 15;
        // r(t): bits {t5, t2, t4, t3, t1, t0}
        const int prow = (row & 32) | ((row & 4) << 2) | ((row & 24) >> 1) | (row & 3);
        const float* src = kp + (((size_t)b * SS + (t0 + row)) * NKV + kh) * DD + c16 * 8;
        float4 a = *(const float4*)src;
        float4 d = *(const float4*)(src + 4);
        *(u32x4*)&kpl[sb][prow][c16 * 8] = __builtin_bit_cast(u32x4, cvt_bf16x8(a, d));
      }
      // V^T: coalesced per-t dword loads -> b128 row-seg writes
      #pragma unroll
      for (int it = 0; it < 2; ++it) {
        const int c  = tid + it * NTHREADS;    // 0..1023
        const int dv = c & 127, t8 = c >> 7;   // d, t-octet
        const float* src = vp + (((size_t)b * SS + (t0 + t8 * 8)) * NKV + kh) * DD + dv;
        bf16x8 e;
        #pragma unroll
        for (int i2 = 0; i2 < 8; ++i2)
          e[i2] = (__bf16)src[(size_t)i2 * (NKV * DD)];
        *(u32x4*)&vtp[sb][dv][t8 * 8] = __builtin_bit_cast(u32x4, e);
      }
    }

    // ---- compute tile ct = tt-1 from buf[ct&1] ----
    if (tt >= 1) {
      const int ct  = tt - 1;
      const int t0c = ct * KVBLK;
      const int cb  = ct & 1;
      if (t0c <= qw + 31) {
        // QK^T swapped, both subtiles share each K read.
        f32x4 sf[2][4];
        #pragma unroll
        for (int cc = 0; cc < 4; ++cc) {
          f32x4 a0 = (f32x4){0.f, 0.f, 0.f, 0.f};
          f32x4 a1 = (f32x4){0.f, 0.f, 0.f, 0.f};
          const int r = cc * 16 + llo;         // permuted K row for A-fragment
          #pragma unroll
          for (int kc = 0; kc < 4; ++kc) {
            u32x4 kb = *(const u32x4*)&kpl[cb][r][(kc * 4 + lhi) * 8];
            const bf16x8 kf = __builtin_bit_cast(bf16x8, kb);
            a0 = __builtin_amdgcn_mfma_f32_16x16x32_bf16(kf, qf[0][kc], a0, 0, 0, 0);
            a1 = __builtin_amdgcn_mfma_f32_16x16x32_bf16(kf, qf[1][kc], a1, 0, 0, 0);
          }
          sf[0][cc] = a0; sf[1][cc] = a1;
        }

        // causal mask (permuted t mapping)
        if (t0c + KVBLK - 1 > qw) {
          #pragma unroll
          for (int u = 0; u < 2; ++u) {
            const int qg = qw + u * 16 + llo;
            #pragma unroll
            for (int cc = 0; cc < 4; ++cc)
              #pragma unroll
              for (int jj = 0; jj < 4; ++jj) {
                const int tg = t0c + (cc >> 1) * 32 + lhi * 8 + (cc & 1) * 4 + jj;
                if (tg > qg) sf[u][cc][jj] = -1e30f;
              }
          }
        }

        // online softmax with defer-max: rescale only when max grew by >5.5
        #pragma unroll
        for (int u = 0; u < 2; ++u) {
          float tmx = sf[u][0][0];
          #pragma unroll
          for (int cc = 0; cc < 4; ++cc)
            #pragma unroll
            for (int jj = 0; jj < 4; ++jj)
              tmx = fmaxf(tmx, sf[u][cc][jj]);
          tmx = fmaxf(tmx, __shfl_xor(tmx, 16));
          tmx = fmaxf(tmx, __shfl_xor(tmx, 32));

          if (!__all(tmx - m_i[u] <= 5.5f)) {
            const float mnew = fmaxf(m_i[u], tmx);
            const float corr = __expf(m_i[u] - mnew);
            m_i[u] = mnew;
            l_i[u] *= corr;
            #pragma unroll
            for (int jj = 0; jj < 4; ++jj) {
              const float cj = __shfl(corr, lhi * 4 + jj);
              #pragma unroll
              for (int f = 0; f < 8; ++f) oacc[u][f][jj] *= cj;
            }
          }
          const float base = m_i[u];
          float ss = 0.f;
          #pragma unroll
          for (int cc = 0; cc < 4; ++cc)
            #pragma unroll
            for (int jj = 0; jj < 4; ++jj) {
              const float pv = __expf(sf[u][cc][jj] - base);  // <= e^5.5 ~ 244
              sf[u][cc][jj] = pv;
              ss += pv;
            }
          ss += __shfl_xor(ss, 16);
          ss += __shfl_xor(ss, 32);
          l_i[u] += ss;
        }

        // PV: pa(kc2) = {sf[2kc2][0..3], sf[2kc2+1][0..3]} lane-local
        #pragma unroll
        for (int kc2 = 0; kc2 < 2; ++kc2) {
          bf16x8 pa[2];
          #pragma unroll
          for (int u = 0; u < 2; ++u) {
            pa[u][0] = (__bf16)sf[u][2 * kc2][0];
            pa[u][1] = (__bf16)sf[u][2 * kc2][1];
            pa[u][2] = (__bf16)sf[u][2 * kc2][2];
            pa[u][3] = (__bf16)sf[u][2 * kc2][3];
            pa[u][4] = (__bf16)sf[u][2 * kc2 + 1][0];
            pa[u][5] = (__bf16)sf[u][2 * kc2 + 1][1];
            pa[u][6] = (__bf16)sf[u][2 * kc2 + 1][2];
            pa[u][7] = (__bf16)sf[u][2 * kc2 + 1][3];
          }
          #pragma unroll
          for (int f = 0; f < 8; ++f) {
            u32x4 vb = *(const u32x4*)&vtp[cb][f * 16 + llo][(kc2 * 4 + lhi) * 8];
            const bf16x8 vf = __builtin_bit_cast(bf16x8, vb);
            oacc[0][f] = __builtin_amdgcn_mfma_f32_16x16x32_bf16(pa[0], vf, oacc[0][f], 0, 0, 0);
            oacc[1][f] = __builtin_amdgcn_mfma_f32_16x16x32_bf16(pa[1], vf, oacc[1][f], 0, 0, 0);
          }
        }
      }
    }

    __syncthreads();   // buf[tt&1] staged for all; buf[(tt-1)&1] reusable
  }

  // ---- epilogue: O / l ----
  #pragma unroll
  for (int u = 0; u < 2; ++u)
    #pragma unroll
    for (int jj = 0; jj < 4; ++jj) {
      const float lj = __shfl(l_i[u], lhi * 4 + jj);
      const float inv = 1.f / lj;
      const int qg = qw + u * 16 + lhi * 4 + jj;
      float* orow = op + (((size_t)b * SS + qg) * NH + h) * DD;
      #pragma unroll
      for (int f = 0; f < 8; ++f)
        orow[f * 16 + llo] = oacc[u][f][jj] * inv;
    }
}

extern "C" void kernel_launch(void* const* d_in, const int* in_sizes, int n_in,
                              void* d_out, int out_size, void* d_ws, size_t ws_size,
                              hipStream_t stream) {
  const float* q = (const float*)d_in[0];
  const float* k = (const float*)d_in[1];
  const float* v = (const float*)d_in[2];
  float* out = (float*)d_out;
  dim3 grid(BB * NH * NQT);   // 512 blocks, heavy-first linear dispatch
  dim3 block(NTHREADS);
  attn_mfma_u2<<<grid, block, 0, stream>>>(q, k, v, out);
}